// Round 1
// baseline (84.795 us; speedup 1.0000x reference)
//
#include <hip/hip_runtime.h>
#include <hip/hip_bf16.h>
#include <math.h>

#define DD 256      // feature dim
#define SS 1024     // seq len
#define BB 8        // batch
#define NN 128      // nodes
#define TOK 16      // tokens per block in scorer
#define NT 8        // nodes per block in pool

// ---------------- Kernel 1: scorer MLP -> scores (B*S) ----------------
// h = x @ W1 + b1 ; LN(h) ; GELU(erf) ; score = h @ W2 + b2
__global__ __launch_bounds__(256) void scorer_kernel(
    const float* __restrict__ doc, const float* __restrict__ W1,
    const float* __restrict__ b1, const float* __restrict__ gamma,
    const float* __restrict__ beta, const float* __restrict__ W2,
    const float* __restrict__ b2, float* __restrict__ scores)
{
    const int tid = threadIdx.x;           // 0..255 == output column j
    const int t0  = blockIdx.x * TOK;      // flattened token base (b*S+s)
    const float* xbase = doc + (size_t)t0 * DD;

    float acc[TOK];
    const float bias = b1[tid];
#pragma unroll
    for (int t = 0; t < TOK; ++t) acc[t] = bias;

    // GEMM: acc[t] = sum_k x[t][k] * W1[k][tid]
    for (int k4 = 0; k4 < DD; k4 += 4) {
        const float w0 = W1[(k4 + 0) * DD + tid];
        const float w1 = W1[(k4 + 1) * DD + tid];
        const float w2 = W1[(k4 + 2) * DD + tid];
        const float w3 = W1[(k4 + 3) * DD + tid];
#pragma unroll
        for (int t = 0; t < TOK; ++t) {
            const float4 xv = *reinterpret_cast<const float4*>(xbase + (size_t)t * DD + k4);
            acc[t] = fmaf(xv.x, w0, acc[t]);
            acc[t] = fmaf(xv.y, w1, acc[t]);
            acc[t] = fmaf(xv.z, w2, acc[t]);
            acc[t] = fmaf(xv.w, w3, acc[t]);
        }
    }

    __shared__ float h[TOK][DD];   // 16 KiB
#pragma unroll
    for (int t = 0; t < TOK; ++t) h[t][tid] = acc[t];
    __syncthreads();

    // per-wave LayerNorm + GELU + dot(W2); 4 waves x 4 tokens
    const int wave = tid >> 6, lane = tid & 63;
#pragma unroll
    for (int i = 0; i < 4; ++i) {
        const int t = wave * 4 + i;
        float v[4];
        float s1 = 0.f, s2 = 0.f;
#pragma unroll
        for (int q = 0; q < 4; ++q) {
            v[q] = h[t][lane + 64 * q];
            s1 += v[q];
            s2 += v[q] * v[q];
        }
#pragma unroll
        for (int off = 32; off > 0; off >>= 1) {
            s1 += __shfl_xor(s1, off, 64);
            s2 += __shfl_xor(s2, off, 64);
        }
        const float mean = s1 * (1.f / DD);
        const float var  = s2 * (1.f / DD) - mean * mean;
        const float inv  = rsqrtf(var + 1e-5f);
        float sc = 0.f;
#pragma unroll
        for (int q = 0; q < 4; ++q) {
            const int j = lane + 64 * q;
            const float nx = (v[q] - mean) * inv * gamma[j] + beta[j];
            const float g  = 0.5f * nx * (1.f + erff(nx * 0.70710678118654752f));
            sc = fmaf(g, W2[j], sc);
        }
#pragma unroll
        for (int off = 32; off > 0; off >>= 1) sc += __shfl_xor(sc, off, 64);
        if (lane == 0) scores[t0 + t] = sc + b2[0];
    }
}

// ---------------- Kernel 2: masked softmax + pooled GEMM ----------------
__global__ __launch_bounds__(256) void pool_kernel(
    const float* __restrict__ doc, const float* __restrict__ mapping,
    const float* __restrict__ scores, float* __restrict__ out)
{
    __shared__ float sc_s[SS];          // 4 KiB
    __shared__ float w_lds[NT][SS];     // 32 KiB
    __shared__ float invz_s[NT];

    const int tid   = threadIdx.x;
    const int blk   = blockIdx.x;
    const int b     = blk / (NN / NT);
    const int ntile = blk % (NN / NT);

    // Phase A: stage scores row
    reinterpret_cast<float4*>(sc_s)[tid] =
        reinterpret_cast<const float4*>(scores + (size_t)b * SS)[tid];
    __syncthreads();

    const int wave = tid >> 6, lane = tid & 63;
    // Phase B: per-node masked max + sum-exp; 4 waves x 2 nodes
#pragma unroll
    for (int i = 0; i < 2; ++i) {
        const int nl = wave * 2 + i;
        const int n  = ntile * NT + nl;
        const float* mrow = mapping + ((size_t)b * NN + n) * SS;
        unsigned bits = 0u;
        float mx = -INFINITY;
        float scr[16];
#pragma unroll
        for (int q = 0; q < 16; ++q) {
            const int s = lane + (q << 6);
            const float mp = mrow[s];
            const float v  = sc_s[s];
            scr[q] = v;
            if (mp > 0.5f) { bits |= (1u << q); mx = fmaxf(mx, v); }
        }
#pragma unroll
        for (int off = 32; off > 0; off >>= 1) mx = fmaxf(mx, __shfl_xor(mx, off, 64));
        float z = 0.f;
#pragma unroll
        for (int q = 0; q < 16; ++q) {
            const int s = lane + (q << 6);
            float e = 0.f;
            if (bits & (1u << q)) e = __expf(scr[q] - mx);
            w_lds[nl][s] = e;
            z += e;
        }
#pragma unroll
        for (int off = 32; off > 0; off >>= 1) z += __shfl_xor(z, off, 64);
        if (lane == 0) invz_s[nl] = (z > 0.f) ? (1.f / z) : 0.f;
    }
    __syncthreads();

    // Phase C: pooled[n][tid] = sum_s w[n][s] * doc[b][s][tid]
    float acc[NT];
#pragma unroll
    for (int n = 0; n < NT; ++n) acc[n] = 0.f;
    const float* docb = doc + (size_t)b * SS * DD;
    for (int s4 = 0; s4 < SS; s4 += 4) {
        const float d0 = docb[(size_t)(s4 + 0) * DD + tid];
        const float d1 = docb[(size_t)(s4 + 1) * DD + tid];
        const float d2 = docb[(size_t)(s4 + 2) * DD + tid];
        const float d3 = docb[(size_t)(s4 + 3) * DD + tid];
#pragma unroll
        for (int n = 0; n < NT; ++n) {
            const float4 wv = *reinterpret_cast<const float4*>(&w_lds[n][s4]);
            acc[n] = fmaf(wv.x, d0, acc[n]);
            acc[n] = fmaf(wv.y, d1, acc[n]);
            acc[n] = fmaf(wv.z, d2, acc[n]);
            acc[n] = fmaf(wv.w, d3, acc[n]);
        }
    }

    // Phase D: scale by 1/Z and store
    float* outb = out + (((size_t)b * NN) + (size_t)ntile * NT) * DD;
#pragma unroll
    for (int n = 0; n < NT; ++n)
        outb[(size_t)n * DD + tid] = acc[n] * invz_s[n];
}

extern "C" void kernel_launch(void* const* d_in, const int* in_sizes, int n_in,
                              void* d_out, int out_size, void* d_ws, size_t ws_size,
                              hipStream_t stream) {
    const float* doc     = (const float*)d_in[0];  // (B,S,D)
    const float* mapping = (const float*)d_in[1];  // (B,N,S)
    // d_in[2] = nodes_len (unused)
    const float* W1    = (const float*)d_in[3];    // (D,D)
    const float* b1    = (const float*)d_in[4];    // (D)
    const float* gamma = (const float*)d_in[5];    // (D)
    const float* beta  = (const float*)d_in[6];    // (D)
    const float* W2    = (const float*)d_in[7];    // (D,1)
    const float* b2    = (const float*)d_in[8];    // (1)
    float* out    = (float*)d_out;                 // (B,N,D)
    float* scores = (float*)d_ws;                  // B*S floats = 32 KiB scratch

    scorer_kernel<<<(BB * SS) / TOK, 256, 0, stream>>>(doc, W1, b1, gamma, beta, W2, b2, scores);
    pool_kernel<<<BB * (NN / NT), 256, 0, stream>>>(doc, mapping, scores, out);
}

// Round 2
// 66.519 us; speedup vs baseline: 1.2747x; 1.2747x over previous
//
#include <hip/hip_runtime.h>
#include <hip/hip_bf16.h>
#include <math.h>

#define DD 256      // feature dim
#define SS 1024     // seq len
#define BB 8        // batch
#define NN 128      // nodes
#define TOK 16      // tokens per block in scorer
#define NT 8        // nodes per tile in pool

// ---------------- Kernel 1: scorer MLP -> scores (B*S) ----------------
// h = x @ W1 + b1 ; LN(h) ; GELU(erf) ; score = h @ W2 + b2
__global__ __launch_bounds__(256) void scorer_kernel(
    const float* __restrict__ doc, const float* __restrict__ W1,
    const float* __restrict__ b1, const float* __restrict__ gamma,
    const float* __restrict__ beta, const float* __restrict__ W2,
    const float* __restrict__ b2, float* __restrict__ scores)
{
    __shared__ float xs[TOK][DD];   // 16 KiB input tile
    __shared__ float h[TOK][DD];    // 16 KiB activations

    const int tid = threadIdx.x;           // 0..255 == output column j
    const int t0  = blockIdx.x * TOK;      // flattened token base (b*S+s)

    // stage x tile: 1024 float4, 4 per thread, coalesced
    {
        const float4* src = reinterpret_cast<const float4*>(doc + (size_t)t0 * DD);
        float4* dst = reinterpret_cast<float4*>(&xs[0][0]);
#pragma unroll
        for (int r = 0; r < 4; ++r) dst[tid + 256 * r] = src[tid + 256 * r];
    }
    __syncthreads();

    float acc[TOK];
    const float bias = b1[tid];
#pragma unroll
    for (int t = 0; t < TOK; ++t) acc[t] = bias;

    // GEMM: acc[t] = sum_k xs[t][k] * W1[k][tid]; depth-2 prefetch on W1
    float w[4], nw[4];
#pragma unroll
    for (int i = 0; i < 4; ++i) w[i] = W1[(size_t)i * DD + tid];
    for (int k4 = 0; k4 < DD - 4; k4 += 4) {
#pragma unroll
        for (int i = 0; i < 4; ++i) nw[i] = W1[(size_t)(k4 + 4 + i) * DD + tid];
#pragma unroll
        for (int t = 0; t < TOK; ++t) {
            const float4 xv = *reinterpret_cast<const float4*>(&xs[t][k4]);
            acc[t] = fmaf(xv.x, w[0], acc[t]);
            acc[t] = fmaf(xv.y, w[1], acc[t]);
            acc[t] = fmaf(xv.z, w[2], acc[t]);
            acc[t] = fmaf(xv.w, w[3], acc[t]);
        }
#pragma unroll
        for (int i = 0; i < 4; ++i) w[i] = nw[i];
    }
    {
        const int k4 = DD - 4;
#pragma unroll
        for (int t = 0; t < TOK; ++t) {
            const float4 xv = *reinterpret_cast<const float4*>(&xs[t][k4]);
            acc[t] = fmaf(xv.x, w[0], acc[t]);
            acc[t] = fmaf(xv.y, w[1], acc[t]);
            acc[t] = fmaf(xv.z, w[2], acc[t]);
            acc[t] = fmaf(xv.w, w[3], acc[t]);
        }
    }

#pragma unroll
    for (int t = 0; t < TOK; ++t) h[t][tid] = acc[t];
    __syncthreads();

    // per-wave LayerNorm + GELU + dot(W2); 4 waves x 4 tokens
    const int wave = tid >> 6, lane = tid & 63;
    float gm[4], be[4], w2[4];
#pragma unroll
    for (int q = 0; q < 4; ++q) {
        const int j = lane + 64 * q;
        gm[q] = gamma[j]; be[q] = beta[j]; w2[q] = W2[j];
    }
    const float b2v = b2[0];
#pragma unroll
    for (int i = 0; i < 4; ++i) {
        const int t = wave * 4 + i;
        float v[4];
        float s1 = 0.f, s2 = 0.f;
#pragma unroll
        for (int q = 0; q < 4; ++q) {
            v[q] = h[t][lane + 64 * q];
            s1 += v[q];
            s2 += v[q] * v[q];
        }
#pragma unroll
        for (int off = 32; off > 0; off >>= 1) {
            s1 += __shfl_xor(s1, off, 64);
            s2 += __shfl_xor(s2, off, 64);
        }
        const float mean = s1 * (1.f / DD);
        const float var  = s2 * (1.f / DD) - mean * mean;
        const float inv  = rsqrtf(var + 1e-5f);
        float sc = 0.f;
#pragma unroll
        for (int q = 0; q < 4; ++q) {
            const float nx = (v[q] - mean) * inv * gm[q] + be[q];
            const float g  = 0.5f * nx * (1.f + erff(nx * 0.70710678118654752f));
            sc = fmaf(g, w2[q], sc);
        }
#pragma unroll
        for (int off = 32; off > 0; off >>= 1) sc += __shfl_xor(sc, off, 64);
        if (lane == 0) scores[t0 + t] = sc + b2v;
    }
}

// ---------------- Kernel 2: per-node masked max + 1/Z ----------------
__global__ __launch_bounds__(256) void stats_kernel(
    const float* __restrict__ mapping, const float* __restrict__ scores,
    float* __restrict__ mx_out, float* __restrict__ invz_out)
{
    __shared__ float sc_s[SS];      // 4 KiB
    const int tid = threadIdx.x, wave = tid >> 6, lane = tid & 63;
    const int g0 = blockIdx.x * 4;        // 4 nodes per block, same batch
    const int b  = g0 >> 7;               // 128 nodes per batch

    reinterpret_cast<float4*>(sc_s)[tid] =
        reinterpret_cast<const float4*>(scores + (size_t)b * SS)[tid];
    __syncthreads();

    const int g = g0 + wave;
    const float* mrow = mapping + (size_t)g * SS;
    float mv[16], sv[16];
    float mx = -INFINITY;
#pragma unroll
    for (int q = 0; q < 16; ++q) {
        const int s = lane + (q << 6);
        mv[q] = mrow[s];
        sv[q] = sc_s[s];
        if (mv[q] > 0.5f) mx = fmaxf(mx, sv[q]);
    }
#pragma unroll
    for (int off = 32; off > 0; off >>= 1) mx = fmaxf(mx, __shfl_xor(mx, off, 64));
    float z = 0.f;
#pragma unroll
    for (int q = 0; q < 16; ++q)
        if (mv[q] > 0.5f) z += __expf(sv[q] - mx);
#pragma unroll
    for (int off = 32; off > 0; off >>= 1) z += __shfl_xor(z, off, 64);
    if (lane == 0) {
        mx_out[g]   = mx;
        invz_out[g] = (z > 0.f) ? (1.f / z) : 0.f;
    }
}

// ---------------- Kernel 3: weighted pool over an S-chunk ----------------
// blockIdx = (b*16 + ntile)*SC + c ; partial[n][d] for NT nodes
template <int SC>
__global__ __launch_bounds__(256) void pool_kernel(
    const float* __restrict__ doc, const float* __restrict__ mapping,
    const float* __restrict__ scores, const float* __restrict__ mx_in,
    const float* __restrict__ invz_in, float* __restrict__ part)
{
    constexpr int SCH = SS / SC;
    __shared__ float w_lds[NT][SCH];

    const int blk   = blockIdx.x;
    const int c     = blk % SC;
    const int bt    = blk / SC;
    const int ntile = bt & 15;
    const int b     = bt >> 4;
    const int s0    = c * SCH;
    const int tid = threadIdx.x, wave = tid >> 6, lane = tid & 63;

    // weights for NT nodes over this chunk: 4 waves x 2 nodes
#pragma unroll
    for (int i = 0; i < 2; ++i) {
        const int nl = wave * 2 + i;
        const int g  = b * NN + ntile * NT + nl;
        const float mx   = mx_in[g];
        const float invz = invz_in[g];
        const float* mrow = mapping + (size_t)g * SS + s0;
        const float* srow = scores + (size_t)b * SS + s0;
#pragma unroll
        for (int q = 0; q < SCH / 64; ++q) {
            const int s = lane + (q << 6);
            const float mp = mrow[s];
            w_lds[nl][s] = (mp > 0.5f) ? __expf(srow[s] - mx) * invz : 0.f;
        }
    }
    __syncthreads();

    float acc[NT];
#pragma unroll
    for (int n = 0; n < NT; ++n) acc[n] = 0.f;
    const float* docb = doc + ((size_t)b * SS + s0) * DD;

    // depth-2 prefetch on doc columns
    float d0 = docb[(size_t)0 * DD + tid], d1 = docb[(size_t)1 * DD + tid];
    float d2 = docb[(size_t)2 * DD + tid], d3 = docb[(size_t)3 * DD + tid];
    for (int s4 = 0; s4 < SCH - 4; s4 += 4) {
        const float n0 = docb[(size_t)(s4 + 4) * DD + tid];
        const float n1 = docb[(size_t)(s4 + 5) * DD + tid];
        const float n2 = docb[(size_t)(s4 + 6) * DD + tid];
        const float n3 = docb[(size_t)(s4 + 7) * DD + tid];
#pragma unroll
        for (int n = 0; n < NT; ++n) {
            const float4 wv = *reinterpret_cast<const float4*>(&w_lds[n][s4]);
            acc[n] = fmaf(wv.x, d0, acc[n]);
            acc[n] = fmaf(wv.y, d1, acc[n]);
            acc[n] = fmaf(wv.z, d2, acc[n]);
            acc[n] = fmaf(wv.w, d3, acc[n]);
        }
        d0 = n0; d1 = n1; d2 = n2; d3 = n3;
    }
    {
        const int s4 = SCH - 4;
#pragma unroll
        for (int n = 0; n < NT; ++n) {
            const float4 wv = *reinterpret_cast<const float4*>(&w_lds[n][s4]);
            acc[n] = fmaf(wv.x, d0, acc[n]);
            acc[n] = fmaf(wv.y, d1, acc[n]);
            acc[n] = fmaf(wv.z, d2, acc[n]);
            acc[n] = fmaf(wv.w, d3, acc[n]);
        }
    }

    float* p = part + (size_t)blk * (NT * DD);
#pragma unroll
    for (int n = 0; n < NT; ++n) p[(size_t)n * DD + tid] = acc[n];
}

// ---------------- Kernel 4: reduce SC partials ----------------
__global__ __launch_bounds__(256) void reduce_kernel(
    const float* __restrict__ part, float* __restrict__ out)
{
    const int o = blockIdx.x * 256 + threadIdx.x;  // grid 1024 -> all B*N*D
    const int d = o & 255;
    const int g = o >> 8;          // 0..1023 global node
    const int b = g >> 7;
    const int n = g & 127;
    const int ntile = n >> 3, nl = n & 7;
    const size_t base = ((size_t)(b * 16 + ntile) * 4) * (NT * DD) + (size_t)nl * DD + d;
    float s = 0.f;
#pragma unroll
    for (int c = 0; c < 4; ++c) s += part[base + (size_t)c * (NT * DD)];
    out[o] = s;
}

extern "C" void kernel_launch(void* const* d_in, const int* in_sizes, int n_in,
                              void* d_out, int out_size, void* d_ws, size_t ws_size,
                              hipStream_t stream) {
    const float* doc     = (const float*)d_in[0];  // (B,S,D)
    const float* mapping = (const float*)d_in[1];  // (B,N,S)
    // d_in[2] = nodes_len (unused)
    const float* W1    = (const float*)d_in[3];    // (D,D)
    const float* b1    = (const float*)d_in[4];    // (D)
    const float* gamma = (const float*)d_in[5];    // (D)
    const float* beta  = (const float*)d_in[6];    // (D)
    const float* W2    = (const float*)d_in[7];    // (D,1)
    const float* b2    = (const float*)d_in[8];    // (1)
    float* out = (float*)d_out;                    // (B,N,D)

    float* scores = (float*)d_ws;                   // B*S = 8192 f32 (32 KiB)
    float* mx     = scores + BB * SS;               // 1024 f32
    float* invz   = mx + BB * NN;                   // 1024 f32
    float* part   = invz + BB * NN;                 // SC=4 partials: 4 MiB

    const size_t need = (size_t)(BB * SS + 2 * BB * NN) * 4
                      + (size_t)BB * 16 * 4 * NT * DD * 4;

    scorer_kernel<<<(BB * SS) / TOK, 256, 0, stream>>>(doc, W1, b1, gamma, beta, W2, b2, scores);
    stats_kernel<<<(BB * NN) / 4, 256, 0, stream>>>(mapping, scores, mx, invz);

    if (ws_size >= need) {
        pool_kernel<4><<<BB * 16 * 4, 256, 0, stream>>>(doc, mapping, scores, mx, invz, part);
        reduce_kernel<<<(BB * NN * DD) / 256, 256, 0, stream>>>(part, out);
    } else {
        // fallback: no chunking, write directly to out (layout matches)
        pool_kernel<1><<<BB * 16, 256, 0, stream>>>(doc, mapping, scores, mx, invz, out);
    }
}

// Round 3
// 58.970 us; speedup vs baseline: 1.4379x; 1.1280x over previous
//
#include <hip/hip_runtime.h>
#include <hip/hip_bf16.h>
#include <math.h>

#define DD 256      // feature dim
#define SS 1024     // seq len
#define BB 8        // batch
#define NN 128      // nodes
#define TOK 16      // tokens per block in scorer
#define NT 8        // nodes per tile in pool

// ---------------- Kernel 1: scorer MLP -> scores (B*S) ----------------
// h = x @ W1 + b1 ; LN(h) ; GELU(erf) ; score = h @ W2 + b2
// Layout: 4 waves/block; wave owns 4 tokens; thread owns 4 columns (c0=4*lane).
__global__ __launch_bounds__(256) void scorer_kernel(
    const float* __restrict__ doc, const float* __restrict__ W1,
    const float* __restrict__ b1, const float* __restrict__ gamma,
    const float* __restrict__ beta, const float* __restrict__ W2,
    const float* __restrict__ b2, float* __restrict__ scores)
{
    __shared__ float xs[TOK][DD];   // 16 KiB input tile

    const int tid  = threadIdx.x;
    const int wave = tid >> 6, lane = tid & 63;
    const int t0   = blockIdx.x * TOK;
    const int c0   = lane * 4;

    // stage x tile: 1024 float4, 4 per thread, coalesced
    {
        const float4* src = reinterpret_cast<const float4*>(doc + (size_t)t0 * DD);
        float4* dst = reinterpret_cast<float4*>(&xs[0][0]);
#pragma unroll
        for (int r = 0; r < 4; ++r) dst[tid + 256 * r] = src[tid + 256 * r];
    }
    __syncthreads();

    const float* xw = &xs[wave * 4][0];   // this wave's 4 token rows

    float4 acc[4];                         // [token] -> 4 cols
    {
        const float4 bv = *reinterpret_cast<const float4*>(b1 + c0);
#pragma unroll
        for (int t = 0; t < 4; ++t) acc[t] = bv;
    }

    // depth-2 pipeline over k4 groups: W1 rows (per-lane float4) + x (broadcast float4)
    float4 w[4], nw[4], xv[4], nxv[4];
#pragma unroll
    for (int i = 0; i < 4; ++i)
        w[i] = *reinterpret_cast<const float4*>(W1 + (size_t)i * DD + c0);
#pragma unroll
    for (int t = 0; t < 4; ++t)
        xv[t] = *reinterpret_cast<const float4*>(xw + (size_t)t * DD);

    for (int k4 = 0; k4 < DD; k4 += 4) {
        if (k4 + 4 < DD) {
#pragma unroll
            for (int i = 0; i < 4; ++i)
                nw[i] = *reinterpret_cast<const float4*>(W1 + (size_t)(k4 + 4 + i) * DD + c0);
#pragma unroll
            for (int t = 0; t < 4; ++t)
                nxv[t] = *reinterpret_cast<const float4*>(xw + (size_t)t * DD + k4 + 4);
        }
#pragma unroll
        for (int t = 0; t < 4; ++t) {
            acc[t].x = fmaf(xv[t].x, w[0].x, acc[t].x);
            acc[t].y = fmaf(xv[t].x, w[0].y, acc[t].y);
            acc[t].z = fmaf(xv[t].x, w[0].z, acc[t].z);
            acc[t].w = fmaf(xv[t].x, w[0].w, acc[t].w);
            acc[t].x = fmaf(xv[t].y, w[1].x, acc[t].x);
            acc[t].y = fmaf(xv[t].y, w[1].y, acc[t].y);
            acc[t].z = fmaf(xv[t].y, w[1].z, acc[t].z);
            acc[t].w = fmaf(xv[t].y, w[1].w, acc[t].w);
            acc[t].x = fmaf(xv[t].z, w[2].x, acc[t].x);
            acc[t].y = fmaf(xv[t].z, w[2].y, acc[t].y);
            acc[t].z = fmaf(xv[t].z, w[2].z, acc[t].z);
            acc[t].w = fmaf(xv[t].z, w[2].w, acc[t].w);
            acc[t].x = fmaf(xv[t].w, w[3].x, acc[t].x);
            acc[t].y = fmaf(xv[t].w, w[3].y, acc[t].y);
            acc[t].z = fmaf(xv[t].w, w[3].z, acc[t].z);
            acc[t].w = fmaf(xv[t].w, w[3].w, acc[t].w);
        }
#pragma unroll
        for (int i = 0; i < 4; ++i) w[i] = nw[i];
#pragma unroll
        for (int t = 0; t < 4; ++t) xv[t] = nxv[t];
    }

    // LayerNorm + GELU + dot(W2) — all in registers + wave shuffles
    const float4 gm = *reinterpret_cast<const float4*>(gamma + c0);
    const float4 be = *reinterpret_cast<const float4*>(beta + c0);
    const float4 w2 = *reinterpret_cast<const float4*>(W2 + c0);
    const float b2v = b2[0];

#pragma unroll
    for (int t = 0; t < 4; ++t) {
        float s1 = acc[t].x + acc[t].y + acc[t].z + acc[t].w;
        float s2 = acc[t].x * acc[t].x + acc[t].y * acc[t].y
                 + acc[t].z * acc[t].z + acc[t].w * acc[t].w;
#pragma unroll
        for (int off = 32; off > 0; off >>= 1) {
            s1 += __shfl_xor(s1, off, 64);
            s2 += __shfl_xor(s2, off, 64);
        }
        const float mean = s1 * (1.f / DD);
        const float var  = s2 * (1.f / DD) - mean * mean;
        const float inv  = rsqrtf(var + 1e-5f);

        float n0 = (acc[t].x - mean) * inv * gm.x + be.x;
        float n1 = (acc[t].y - mean) * inv * gm.y + be.y;
        float n2 = (acc[t].z - mean) * inv * gm.z + be.z;
        float n3 = (acc[t].w - mean) * inv * gm.w + be.w;
        const float kq = 0.70710678118654752f;
        float g0 = 0.5f * n0 * (1.f + erff(n0 * kq));
        float g1 = 0.5f * n1 * (1.f + erff(n1 * kq));
        float g2 = 0.5f * n2 * (1.f + erff(n2 * kq));
        float g3 = 0.5f * n3 * (1.f + erff(n3 * kq));
        float sc = g0 * w2.x + g1 * w2.y + g2 * w2.z + g3 * w2.w;
#pragma unroll
        for (int off = 32; off > 0; off >>= 1) sc += __shfl_xor(sc, off, 64);
        if (lane == 0) scores[t0 + wave * 4 + t] = sc + b2v;
    }
}

// ---------------- Kernel 2: per-node masked max + 1/Z ----------------
__global__ __launch_bounds__(256) void stats_kernel(
    const float* __restrict__ mapping, const float* __restrict__ scores,
    float* __restrict__ mx_out, float* __restrict__ invz_out)
{
    __shared__ float sc_s[SS];      // 4 KiB
    const int tid = threadIdx.x, wave = tid >> 6, lane = tid & 63;
    const int g0 = blockIdx.x * 4;        // 4 nodes per block, same batch
    const int b  = g0 >> 7;               // 128 nodes per batch

    reinterpret_cast<float4*>(sc_s)[tid] =
        reinterpret_cast<const float4*>(scores + (size_t)b * SS)[tid];
    __syncthreads();

    const int g = g0 + wave;
    const float* mrow = mapping + (size_t)g * SS;
    float mv[16], sv[16];
    float mx = -INFINITY;
#pragma unroll
    for (int q = 0; q < 16; ++q) {
        const int s = lane + (q << 6);
        mv[q] = mrow[s];
        sv[q] = sc_s[s];
        if (mv[q] > 0.5f) mx = fmaxf(mx, sv[q]);
    }
#pragma unroll
    for (int off = 32; off > 0; off >>= 1) mx = fmaxf(mx, __shfl_xor(mx, off, 64));
    float z = 0.f;
#pragma unroll
    for (int q = 0; q < 16; ++q)
        if (mv[q] > 0.5f) z += __expf(sv[q] - mx);
#pragma unroll
    for (int off = 32; off > 0; off >>= 1) z += __shfl_xor(z, off, 64);
    if (lane == 0) {
        mx_out[g]   = mx;
        invz_out[g] = (z > 0.f) ? (1.f / z) : 0.f;
    }
}

// ---------------- Kernel 3: weighted pool over an S-chunk ----------------
// blockIdx = (b*16 + ntile)*SC + c ; partial[n][d] for NT nodes
template <int SC>
__global__ __launch_bounds__(256) void pool_kernel(
    const float* __restrict__ doc, const float* __restrict__ mapping,
    const float* __restrict__ scores, const float* __restrict__ mx_in,
    const float* __restrict__ invz_in, float* __restrict__ part)
{
    constexpr int SCH = SS / SC;
    __shared__ float w_lds[NT][SCH];

    const int blk   = blockIdx.x;
    const int c     = blk % SC;
    const int bt    = blk / SC;
    const int ntile = bt & 15;
    const int b     = bt >> 4;
    const int s0    = c * SCH;
    const int tid = threadIdx.x, wave = tid >> 6, lane = tid & 63;

    // weights for NT nodes over this chunk: 4 waves x 2 nodes
#pragma unroll
    for (int i = 0; i < 2; ++i) {
        const int nl = wave * 2 + i;
        const int g  = b * NN + ntile * NT + nl;
        const float mx   = mx_in[g];
        const float invz = invz_in[g];
        const float* mrow = mapping + (size_t)g * SS + s0;
        const float* srow = scores + (size_t)b * SS + s0;
#pragma unroll
        for (int q = 0; q < SCH / 64; ++q) {
            const int s = lane + (q << 6);
            const float mp = mrow[s];
            w_lds[nl][s] = (mp > 0.5f) ? __expf(srow[s] - mx) * invz : 0.f;
        }
    }
    __syncthreads();

    float acc[NT];
#pragma unroll
    for (int n = 0; n < NT; ++n) acc[n] = 0.f;
    const float* docb = doc + ((size_t)b * SS + s0) * DD;

    // depth-2 prefetch on doc columns
    float d0 = docb[(size_t)0 * DD + tid], d1 = docb[(size_t)1 * DD + tid];
    float d2 = docb[(size_t)2 * DD + tid], d3 = docb[(size_t)3 * DD + tid];
    for (int s4 = 0; s4 < SCH - 4; s4 += 4) {
        const float n0 = docb[(size_t)(s4 + 4) * DD + tid];
        const float n1 = docb[(size_t)(s4 + 5) * DD + tid];
        const float n2 = docb[(size_t)(s4 + 6) * DD + tid];
        const float n3 = docb[(size_t)(s4 + 7) * DD + tid];
#pragma unroll
        for (int n = 0; n < NT; ++n) {
            const float4 wv = *reinterpret_cast<const float4*>(&w_lds[n][s4]);
            acc[n] = fmaf(wv.x, d0, acc[n]);
            acc[n] = fmaf(wv.y, d1, acc[n]);
            acc[n] = fmaf(wv.z, d2, acc[n]);
            acc[n] = fmaf(wv.w, d3, acc[n]);
        }
        d0 = n0; d1 = n1; d2 = n2; d3 = n3;
    }
    {
        const int s4 = SCH - 4;
#pragma unroll
        for (int n = 0; n < NT; ++n) {
            const float4 wv = *reinterpret_cast<const float4*>(&w_lds[n][s4]);
            acc[n] = fmaf(wv.x, d0, acc[n]);
            acc[n] = fmaf(wv.y, d1, acc[n]);
            acc[n] = fmaf(wv.z, d2, acc[n]);
            acc[n] = fmaf(wv.w, d3, acc[n]);
        }
    }

    float* p = part + (size_t)blk * (NT * DD);
#pragma unroll
    for (int n = 0; n < NT; ++n) p[(size_t)n * DD + tid] = acc[n];
}

// ---------------- Kernel 4: reduce SC partials ----------------
__global__ __launch_bounds__(256) void reduce_kernel(
    const float* __restrict__ part, float* __restrict__ out)
{
    const int o = blockIdx.x * 256 + threadIdx.x;  // grid 1024 -> all B*N*D
    const int d = o & 255;
    const int g = o >> 8;          // 0..1023 global node
    const int b = g >> 7;
    const int n = g & 127;
    const int ntile = n >> 3, nl = n & 7;
    const size_t base = ((size_t)(b * 16 + ntile) * 4) * (NT * DD) + (size_t)nl * DD + d;
    float s = 0.f;
#pragma unroll
    for (int c = 0; c < 4; ++c) s += part[base + (size_t)c * (NT * DD)];
    out[o] = s;
}

extern "C" void kernel_launch(void* const* d_in, const int* in_sizes, int n_in,
                              void* d_out, int out_size, void* d_ws, size_t ws_size,
                              hipStream_t stream) {
    const float* doc     = (const float*)d_in[0];  // (B,S,D)
    const float* mapping = (const float*)d_in[1];  // (B,N,S)
    // d_in[2] = nodes_len (unused)
    const float* W1    = (const float*)d_in[3];    // (D,D)
    const float* b1    = (const float*)d_in[4];    // (D)
    const float* gamma = (const float*)d_in[5];    // (D)
    const float* beta  = (const float*)d_in[6];    // (D)
    const float* W2    = (const float*)d_in[7];    // (D,1)
    const float* b2    = (const float*)d_in[8];    // (1)
    float* out = (float*)d_out;                    // (B,N,D)

    float* scores = (float*)d_ws;                   // B*S = 8192 f32 (32 KiB)
    float* mx     = scores + BB * SS;               // 1024 f32
    float* invz   = mx + BB * NN;                   // 1024 f32
    float* part   = invz + BB * NN;                 // SC=4 partials: 4 MiB

    const size_t need = (size_t)(BB * SS + 2 * BB * NN) * 4
                      + (size_t)BB * 16 * 4 * NT * DD * 4;

    scorer_kernel<<<(BB * SS) / TOK, 256, 0, stream>>>(doc, W1, b1, gamma, beta, W2, b2, scores);
    stats_kernel<<<(BB * NN) / 4, 256, 0, stream>>>(mapping, scores, mx, invz);

    if (ws_size >= need) {
        pool_kernel<4><<<BB * 16 * 4, 256, 0, stream>>>(doc, mapping, scores, mx, invz, part);
        reduce_kernel<<<(BB * NN * DD) / 256, 256, 0, stream>>>(part, out);
    } else {
        // fallback: no chunking, write directly to out (layout matches)
        pool_kernel<1><<<BB * 16, 256, 0, stream>>>(doc, mapping, scores, mx, invz, out);
    }
}